// Round 1
// baseline (143.537 us; speedup 1.0000x reference)
//
#include <hip/hip_runtime.h>
#include <hip/hip_bf16.h>
#include <stdint.h>

// SVDHead: scores=softmax(QK^T/sqrt(dk)) over m; corr = scores @ src(3);
// H = (target-mu_t)^T (corr-mu_c); R,t from 3x3 SVD (Kabsch).
// Q=src_embedding [16,2048,512] f32, K=target_embedding, V=src [16,2048,3],
// target [16,2048,3]. Out: R [16,3,3] then t [16,1,3] (192 f32).

#define B_  16
#define N_  2048
#define DK_ 512
#define SCALE 0.044194173824159216f  // 1/sqrt(512)

typedef __bf16 bf16x8 __attribute__((ext_vector_type(8)));
typedef float  f32x16 __attribute__((ext_vector_type(16)));
typedef float  f32x4  __attribute__((ext_vector_type(4)));

union BF8 { bf16x8 v; unsigned u[4]; };

__device__ inline unsigned pkbf(float a, float b) {
  unsigned r;
  asm("v_cvt_pk_bf16_f32 %0, %1, %2" : "=v"(r) : "v"(a), "v"(b));
  return r;
}

// ---------------------------------------------------------------------------
// Kernel 1: attention row-stats. Each block: one (batch, 256-q-rows, m-chunk).
// 8 waves x 32 q-rows. Swapped MFMA: out[m][q] so each lane owns one q col.
// Writes per-row partials [ms][b][n][{a0,a1,a2,l}] (pure sums over m-chunk).
// ---------------------------------------------------------------------------
__global__ __launch_bounds__(512, 2)
void attn_stats_kernel(const float* __restrict__ Q, const float* __restrict__ K,
                       const float* __restrict__ Vsrc, float* __restrict__ part)
{
  __shared__ __align__(16) unsigned char s_k[32 * 1024];  // 32 m x 512 d bf16, swizzled
  __shared__ __align__(16) float s_srcT[3 * 1024];        // srcT[c][m] fp32

  const int L   = blockIdx.x;
  const int xcd = L & 7;          // assumed round-robin XCD mapping
  const int kk  = L >> 3;
  const int b   = xcd + 8 * (kk & 1);   // 2 batches per XCD -> K fits its L2
  const int ms  = (kk >> 1) & 1;        // m-chunk 0/1 (1024 each)
  const int nb  = kk >> 2;              // q-block 0..7 (256 rows each)

  const int tid  = threadIdx.x;
  const int lane = tid & 63;
  const int wid  = tid >> 6;
  const int row  = lane & 31;
  const int hi   = lane >> 5;

  const int mchunk0 = ms * 1024;

  // stage srcT: s_srcT[c][m] = Vsrc[b][mchunk0+m][c]
  {
    const float* vp = Vsrc + ((size_t)b * N_ + mchunk0) * 3;
    for (int idx = tid; idx < 3072; idx += 512) {
      int m = idx / 3, c = idx - 3 * m;
      s_srcT[c * 1024 + m] = vp[idx];
    }
  }

  // Q fragments in registers: lane holds Q[qglob][d=16t+8hi .. +8) as bf16x8
  const int qglob = nb * 256 + wid * 32 + row;
  BF8 qf[32];
  {
    const f32x4* qp = (const f32x4*)(Q + ((size_t)b * N_ + qglob) * DK_);
    #pragma unroll
    for (int t = 0; t < 32; ++t) {
      f32x4 f0 = qp[t * 4 + hi * 2];
      f32x4 f1 = qp[t * 4 + hi * 2 + 1];
      qf[t].u[0] = pkbf(f0[0], f0[1]);
      qf[t].u[1] = pkbf(f0[2], f0[3]);
      qf[t].u[2] = pkbf(f1[0], f1[1]);
      qf[t].u[3] = pkbf(f1[2], f1[3]);
    }
  }

  const f32x4* kg = (const f32x4*)(K + ((size_t)b * N_ + mchunk0) * DK_);

  float lsum = 0.f, a0 = 0.f, a1 = 0.f, a2 = 0.f;

  // prefetch tile 0 (f32x4 index = i*512 + tid, lane-contiguous -> coalesced)
  f32x4 stg[8];
  #pragma unroll
  for (int i = 0; i < 8; ++i) stg[i] = kg[i * 512 + tid];

  const unsigned kread_base = (unsigned)(row * 1024);
  const unsigned kread_xor  = (unsigned)(row << 4);   // bank-conflict swizzle

  for (int tile = 0; tile < 32; ++tile) {
    __syncthreads();  // K-tile LDS free to overwrite
    // write staged fp32 -> bf16 LDS, swizzled: byte = r*1024 + (col8 ^ (r<<4))
    #pragma unroll
    for (int i = 0; i < 8; ++i) {
      int idx  = i * 512 + tid;        // f32x4 index in 32x512 tile
      int r    = idx >> 7;             // m-row 0..31
      int colb = (idx & 127) * 8;      // byte col (bf16 row is 1024 B)
      unsigned addr = (unsigned)(r * 1024) + ((unsigned)colb ^ ((unsigned)(r << 4)));
      uint2 w2;
      w2.x = pkbf(stg[i][0], stg[i][1]);
      w2.y = pkbf(stg[i][2], stg[i][3]);
      *(uint2*)(s_k + addr) = w2;
    }
    __syncthreads();
    // prefetch next tile (latency hides under MFMA phase)
    if (tile + 1 < 32) {
      const f32x4* kt = kg + (size_t)(tile + 1) * 4096;
      #pragma unroll
      for (int i = 0; i < 8; ++i) stg[i] = kt[i * 512 + tid];
    }
    // scores: 32 MFMA (2 accumulator chains), out[m][q]
    f32x16 sc0, sc1;
    #pragma unroll
    for (int i = 0; i < 16; ++i) { sc0[i] = 0.f; sc1[i] = 0.f; }
    #pragma unroll
    for (int t = 0; t < 32; t += 2) {
      BF8 kf0, kf1;
      kf0.v = *(const bf16x8*)(s_k + kread_base +
                (((unsigned)(t * 32 + hi * 16)) ^ kread_xor));
      sc0 = __builtin_amdgcn_mfma_f32_32x32x16_bf16(kf0.v, qf[t].v, sc0, 0, 0, 0);
      kf1.v = *(const bf16x8*)(s_k + kread_base +
                (((unsigned)((t + 1) * 32 + hi * 16)) ^ kread_xor));
      sc1 = __builtin_amdgcn_mfma_f32_32x32x16_bf16(kf1.v, qf[t + 1].v, sc1, 0, 0, 0);
    }
    // softmax terms (no max subtraction: |s/sqrt(dk)| small) + PV partials.
    // C layout: col=lane&31 (=q), row m = (reg&3) + 8*(reg>>2) + 4*hi.
    // srcT reads are wave-uniform (broadcast, conflict-free).
    #pragma unroll
    for (int j = 0; j < 4; ++j) {
      const int mrun = tile * 32 + j * 8 + hi * 4;
      f32x4 s0 = *(const f32x4*)&s_srcT[mrun];
      f32x4 s1 = *(const f32x4*)&s_srcT[1024 + mrun];
      f32x4 s2 = *(const f32x4*)&s_srcT[2048 + mrun];
      #pragma unroll
      for (int i2 = 0; i2 < 4; ++i2) {
        float w = __expf((sc0[j * 4 + i2] + sc1[j * 4 + i2]) * SCALE);
        lsum += w;
        a0 += w * s0[i2];
        a1 += w * s1[i2];
        a2 += w * s2[i2];
      }
    }
  }

  // lanes l and l+32 hold complementary m-subsets of the same q column
  a0   += __shfl_xor(a0, 32);
  a1   += __shfl_xor(a1, 32);
  a2   += __shfl_xor(a2, 32);
  lsum += __shfl_xor(lsum, 32);

  if (hi == 0) {
    f32x4 o; o[0] = a0; o[1] = a1; o[2] = a2; o[3] = lsum;
    *(f32x4*)(part + (((size_t)ms * B_ + b) * N_ + qglob) * 4) = o;
  }
}

// ---------------------------------------------------------------------------
// Kernel 2: per-batch reduction -> [sum_t(3), sum_corr(3), S=sum t*corr^T(9)]
// ---------------------------------------------------------------------------
__global__ void reduce_kernel(const float* __restrict__ part,
                              const float* __restrict__ tgt,
                              float* __restrict__ ws2)
{
  const int b = blockIdx.x, tid = threadIdx.x;
  float s[15];
  #pragma unroll
  for (int j = 0; j < 15; ++j) s[j] = 0.f;

  for (int n = tid; n < N_; n += 256) {
    f32x4 p0 = *(const f32x4*)(part + (((size_t)0 * B_ + b) * N_ + n) * 4);
    f32x4 p1 = *(const f32x4*)(part + (((size_t)1 * B_ + b) * N_ + n) * 4);
    float inv = 1.0f / (p0[3] + p1[3]);
    float c0 = (p0[0] + p1[0]) * inv;
    float c1 = (p0[1] + p1[1]) * inv;
    float c2 = (p0[2] + p1[2]) * inv;
    const float* tp = tgt + ((size_t)b * N_ + n) * 3;
    float t0 = tp[0], t1 = tp[1], t2 = tp[2];
    s[0] += t0;  s[1] += t1;  s[2] += t2;
    s[3] += c0;  s[4] += c1;  s[5] += c2;
    s[6] += t0 * c0;  s[7]  += t0 * c1;  s[8]  += t0 * c2;
    s[9] += t1 * c0;  s[10] += t1 * c1;  s[11] += t1 * c2;
    s[12] += t2 * c0; s[13] += t2 * c1;  s[14] += t2 * c2;
  }
  #pragma unroll
  for (int j = 0; j < 15; ++j) {
    #pragma unroll
    for (int off = 32; off > 0; off >>= 1) s[j] += __shfl_xor(s[j], off);
  }
  __shared__ float red[4][15];
  int lane = tid & 63, w = tid >> 6;
  if (lane == 0) {
    #pragma unroll
    for (int j = 0; j < 15; ++j) red[w][j] = s[j];
  }
  __syncthreads();
  if (tid < 15)
    ws2[b * 16 + tid] = red[0][tid] + red[1][tid] + red[2][tid] + red[3][tid];
}

// ---------------------------------------------------------------------------
// Kernel 3: 3x3 SVD (double Jacobi on H^T H) + Kabsch R, t. 1 thread/batch.
// R = u1 v1^T + u2 v2^T + det(V) * (u1 x u2) v3^T  (invariant to sign picks)
// ---------------------------------------------------------------------------
__device__ inline void jrot(double A[3][3], double V[3][3], int p, int q) {
  double apq = A[p][q];
  if (fabs(apq) < 1e-300) return;
  double tau = (A[q][q] - A[p][p]) / (2.0 * apq);
  double tt = (tau >= 0.0) ? 1.0 / (tau + sqrt(1.0 + tau * tau))
                           : 1.0 / (tau - sqrt(1.0 + tau * tau));
  double c = 1.0 / sqrt(1.0 + tt * tt), sn = tt * c;
  for (int k = 0; k < 3; ++k) {
    double akp = A[k][p], akq = A[k][q];
    A[k][p] = c * akp - sn * akq;
    A[k][q] = sn * akp + c * akq;
  }
  for (int k = 0; k < 3; ++k) {
    double apk = A[p][k], aqk = A[q][k];
    A[p][k] = c * apk - sn * aqk;
    A[q][k] = sn * apk + c * aqk;
  }
  for (int k = 0; k < 3; ++k) {
    double vkp = V[k][p], vkq = V[k][q];
    V[k][p] = c * vkp - sn * vkq;
    V[k][q] = sn * vkp + c * vkq;
  }
}

__global__ void svd_kernel(const float* __restrict__ ws2, float* __restrict__ out)
{
  const int b = threadIdx.x;
  if (b >= B_) return;
  const float* s = ws2 + b * 16;
  const double invN = 1.0 / (double)N_;
  double stv[3] = {s[0], s[1], s[2]};
  double scv[3] = {s[3], s[4], s[5]};
  double H[3][3];
  for (int c = 0; c < 3; ++c)
    for (int d = 0; d < 3; ++d)
      H[c][d] = (double)s[6 + c * 3 + d] - stv[c] * scv[d] * invN;

  double A[3][3], V[3][3] = {{1,0,0},{0,1,0},{0,0,1}};
  for (int i = 0; i < 3; ++i)
    for (int j = 0; j < 3; ++j) {
      double acc = 0.0;
      for (int c = 0; c < 3; ++c) acc += H[c][i] * H[c][j];
      A[i][j] = acc;
    }
  for (int sw = 0; sw < 15; ++sw) { jrot(A,V,0,1); jrot(A,V,0,2); jrot(A,V,1,2); }

  double e[3] = {A[0][0], A[1][1], A[2][2]};
  double vc[3][3];
  for (int k = 0; k < 3; ++k)
    for (int i = 0; i < 3; ++i) vc[k][i] = V[i][k];
  for (int a2 = 0; a2 < 2; ++a2)
    for (int b2 = 0; b2 < 2 - a2; ++b2)
      if (e[b2] < e[b2 + 1]) {
        double te = e[b2]; e[b2] = e[b2 + 1]; e[b2 + 1] = te;
        for (int i = 0; i < 3; ++i) {
          double tv = vc[b2][i]; vc[b2][i] = vc[b2 + 1][i]; vc[b2 + 1][i] = tv;
        }
      }

  double u1[3], u2[3], u3[3];
  for (int i = 0; i < 3; ++i)
    u1[i] = H[i][0]*vc[0][0] + H[i][1]*vc[0][1] + H[i][2]*vc[0][2];
  double n1 = sqrt(u1[0]*u1[0] + u1[1]*u1[1] + u1[2]*u1[2]);
  n1 = fmax(n1, 1e-300);
  for (int i = 0; i < 3; ++i) u1[i] /= n1;
  for (int i = 0; i < 3; ++i)
    u2[i] = H[i][0]*vc[1][0] + H[i][1]*vc[1][1] + H[i][2]*vc[1][2];
  double d12 = u1[0]*u2[0] + u1[1]*u2[1] + u1[2]*u2[2];
  for (int i = 0; i < 3; ++i) u2[i] -= d12 * u1[i];
  double n2 = sqrt(u2[0]*u2[0] + u2[1]*u2[1] + u2[2]*u2[2]);
  n2 = fmax(n2, 1e-300);
  for (int i = 0; i < 3; ++i) u2[i] /= n2;
  u3[0] = u1[1]*u2[2] - u1[2]*u2[1];
  u3[1] = u1[2]*u2[0] - u1[0]*u2[2];
  u3[2] = u1[0]*u2[1] - u1[1]*u2[0];

  double detV = vc[0][0]*(vc[1][1]*vc[2][2] - vc[1][2]*vc[2][1])
              - vc[0][1]*(vc[1][0]*vc[2][2] - vc[1][2]*vc[2][0])
              + vc[0][2]*(vc[1][0]*vc[2][1] - vc[1][1]*vc[2][0]);

  double R[3][3];
  for (int i = 0; i < 3; ++i)
    for (int j = 0; j < 3; ++j)
      R[i][j] = u1[i]*vc[0][j] + u2[i]*vc[1][j] + detV * u3[i]*vc[2][j];

  for (int i = 0; i < 3; ++i)
    for (int j = 0; j < 3; ++j)
      out[b * 9 + i * 3 + j] = (float)R[i][j];

  double muc[3] = {scv[0]*invN, scv[1]*invN, scv[2]*invN};
  for (int i = 0; i < 3; ++i) {
    double ti = stv[i]*invN - (R[i][0]*muc[0] + R[i][1]*muc[1] + R[i][2]*muc[2]);
    out[B_ * 9 + b * 3 + i] = (float)ti;
  }
}

// ---------------------------------------------------------------------------
extern "C" void kernel_launch(void* const* d_in, const int* in_sizes, int n_in,
                              void* d_out, int out_size, void* d_ws, size_t ws_size,
                              hipStream_t stream)
{
  const float* srcE = (const float*)d_in[0];  // Q
  const float* tgtE = (const float*)d_in[1];  // K
  const float* srcP = (const float*)d_in[2];  // V (3-wide)
  const float* tgtP = (const float*)d_in[3];  // target points
  float* out  = (float*)d_out;
  float* part = (float*)d_ws;                         // 2*16*2048*4 floats = 1 MB
  float* ws2  = part + (size_t)2 * B_ * N_ * 4;       // 16*16 floats

  attn_stats_kernel<<<dim3(256), dim3(512), 0, stream>>>(srcE, tgtE, srcP, part);
  reduce_kernel<<<dim3(B_), dim3(256), 0, stream>>>(part, tgtP, ws2);
  svd_kernel<<<dim3(1), dim3(64), 0, stream>>>(ws2, out);
}